// Round 9
// baseline (23.801 us; speedup 1.0000x reference)
//
#include <hip/hip_runtime.h>
#include <math.h>

#define DD 15          // feature dim
#define DP 20          // padded LDS row stride (80B, float4-aligned)
#define LL 64          // leaves
#define NCC 10         // num classes
#define NTREE 63       // internal nodes only (levels 0..5)
#define EPB 4          // batch elements per block (1 per wave)
#define REPS 3         // discriminator: repeat tree computation (identical results)

// ---- DPP cross-lane (VALU pipe, no LDS) ----
__device__ __forceinline__ float dpp_xor1(float x) {   // quad_perm [1,0,3,2]
    return __int_as_float(__builtin_amdgcn_update_dpp(0, __float_as_int(x), 0xB1, 0xF, 0xF, true));
}
__device__ __forceinline__ float dpp_xor2(float x) {   // quad_perm [2,3,0,1]
    return __int_as_float(__builtin_amdgcn_update_dpp(0, __float_as_int(x), 0x4E, 0xF, 0xF, true));
}
__device__ __forceinline__ float dpp_hmirror(float x) { // row_half_mirror: u -> u^7 within 8
    return __int_as_float(__builtin_amdgcn_update_dpp(0, __float_as_int(x), 0x141, 0xF, 0xF, true));
}

// combine at one parent: 8 lanes cooperate.
// k = t&1 (W matrix), qr = (t>>1)&3 (4 A-rows), u = t&7 (2 output dims)
__device__ __forceinline__ void combine8_core(const float* Lrow, const float* Rrow,
                                              const float w[4][DD], int k, int qr, int u,
                                              float& o0, float& o1)
{
    float4 R0 = ((const float4*)Rrow)[0];
    float4 R1 = ((const float4*)Rrow)[1];
    float4 R2 = ((const float4*)Rrow)[2];
    float4 R3 = ((const float4*)Rrow)[3];          // .w = pad col15 = 0
    float4 Aq = ((const float4*)Lrow)[qr];         // A dims 4qr..4qr+3 (row15 pad = 0)
    float Bv[DD] = {R0.x,R0.y,R0.z,R0.w, R1.x,R1.y,R1.z,R1.w,
                    R2.x,R2.y,R2.z,R2.w, R3.x,R3.y,R3.z};
    float Av[4] = {Aq.x, Aq.y, Aq.z, Aq.w};

    float p = 0.f;
    #pragma unroll
    for (int ri = 0; ri < 4; ++ri) {
        float dA = 0.f, dB = 0.f;                  // 2-way split: chain depth 8 not 15
        #pragma unroll
        for (int j = 0; j < 8; ++j)  dA = fmaf(w[ri][j], Bv[j], dA);
        #pragma unroll
        for (int j = 8; j < DD; ++j) dB = fmaf(w[ri][j], Bv[j], dB);
        p = fmaf(Av[ri], dA + dB, p);              // invalid row 15: w==0, Av==0
    }
    // reduce partials over qr bits (1,2) and swap k — all DPP
    float a    = p + dpp_xor2(p);
    float hma  = dpp_hmirror(a);
    float self = a + dpp_xor1(hma);
    float oth  = dpp_xor1(a) + hma;
    float mx = fmaxf(self, oth);
    float es = __expf(self - mx), eo = __expf(oth - mx);
    float rs = __builtin_amdgcn_rcpf(es + eo);
    float aS = es * rs, aO = eo * rs;
    float a0 = (k == 0) ? aS : aO;                 // alpha for W0 (left child)
    float a1 = (k == 0) ? aO : aS;

    float2 lm = ((const float2*)Lrow)[u];          // dims 2u, 2u+1
    float2 rm = ((const float2*)Rrow)[u];
    float v0 = a0 * lm.x + a1 * rm.x;
    float v1 = a0 * lm.y + a1 * rm.y;              // u==7: dim15 = 0
    float ss = v0 * v0 + v1 * v1;
    ss += dpp_xor1(ss);
    ss += dpp_xor2(ss);
    ss += dpp_hmirror(ss);
    float inv = __builtin_amdgcn_rsqf(ss * (1.0f / DD) + 1e-6f);
    o0 = v0 * inv; o1 = v1 * inv;
}

// ---- build level 5: children are nemb rows selected by preloaded x indices ----
__device__ __forceinline__ void build_level5(float (*tw)[DP], const float (*nemb)[DP],
                                             const float w[4][DD],
                                             const int xA[4], const int xB[4],
                                             int k, int qr, int u, int g)
{
    #pragma unroll
    for (int st = 0; st < 4; ++st) {
        int pi = st * 8 + g;
        float o0, o1;
        combine8_core(&nemb[xA[st]][0], &nemb[xB[st]][0], w, k, qr, u, o0, o1);
        ((float2*)&tw[31 + pi][0])[u] = make_float2(o0, o1);
    }
}

// ---- query level 5: boundary nodes; children are leaves (nemb rows or inf) ----
__device__ __forceinline__ void query_level5(float (*tw)[DP], const float (*nemb)[DP],
                                             const float w[4][DD], int t, int k, int qr, int u,
                                             int ql, int qh, int xq1, int xq2)
{
    const int g2 = (t >> 3) & 1;
    int bnd = g2 ? qh : ql;
    int piB = bnd >> 1;
    int lo = 2 * piB, hi = lo + 1;
    bool full = (ql <= lo) && (qh >= hi);
    bool d1 = (ql > lo) || (qh < lo);
    bool d2 = (ql > hi) || (qh < hi);
    const float* Lrow = d1 ? &nemb[NCC][0] : &nemb[xq1][0];
    const float* Rrow = d2 ? &nemb[NCC][0] : &nemb[xq2][0];
    float o0, o1;
    combine8_core(Lrow, Rrow, w, k, qr, u, o0, o1);
    bool we = (!full) && (t < 16) && (g2 == 0 || piB != (ql >> 1));
    if (we) ((float2*)&tw[31 + piB][0])[u] = make_float2(o0, o1);
}

// ---- generic build (levels 1..4) ----
template<int LVL>
__device__ __forceinline__ void build_level(float (*tw)[DP], const float w[4][DD],
                                            int k, int qr, int u, int g)
{
    constexpr int n = 1 << LVL, first = n - 1, nst = (n + 7) / 8;
    #pragma unroll
    for (int st = 0; st < nst; ++st) {
        int pi0 = st * 8 + g;
        int pi = (n < 8) ? ((pi0 < n) ? pi0 : 0) : pi0;   // clamp keeps reads in-bounds
        int p = first + pi;
        float o0, o1;
        combine8_core(&tw[2 * p + 1][0], &tw[2 * p + 2][0], w, k, qr, u, o0, o1);
        if (pi0 < n)
            ((float2*)&tw[p][0])[u] = make_float2(o0, o1);
    }
}

// ---- generic query (levels 1..4): children in tree ----
template<int LVL>
__device__ __forceinline__ void query_level(float (*tw)[DP], const float (*nemb)[DP],
                                            const float w[4][DD], int t, int k, int qr, int u,
                                            int ql, int qh)
{
    constexpr int first = (1 << LVL) - 1;
    constexpr int sh = 6 - LVL;
    constexpr int shc = sh - 1;
    const int g2 = (t >> 3) & 1;
    int bnd = g2 ? qh : ql;
    int pi = bnd >> sh;
    int lo = pi << sh, hi = lo + (1 << sh) - 1;
    bool full = (ql <= lo) && (qh >= hi);
    int p = first + pi;
    int ci1 = 2 * pi, ci2 = 2 * pi + 1;
    int lo1 = ci1 << shc, hi1 = lo1 + (1 << shc) - 1;
    int lo2 = ci2 << shc, hi2 = lo2 + (1 << shc) - 1;
    bool d1 = (ql > hi1) || (qh < lo1);
    bool d2 = (ql > hi2) || (qh < lo2);
    const float* Lrow = d1 ? &nemb[NCC][0] : &tw[2 * p + 1][0];
    const float* Rrow = d2 ? &nemb[NCC][0] : &tw[2 * p + 2][0];
    float o0, o1;
    combine8_core(Lrow, Rrow, w, k, qr, u, o0, o1);
    bool we = (!full) && (t < 16) && (g2 == 0 || pi != (ql >> sh));
    if (we) ((float2*)&tw[p][0])[u] = make_float2(o0, o1);
}

// ---- query level 0: always write (covers the root-full case) ----
__device__ __forceinline__ void query_level0(float (*tw)[DP], const float (*nemb)[DP],
                                             const float w[4][DD], int t, int k, int qr, int u,
                                             int ql, int qh)
{
    bool d1 = (ql > 31);             // left child [0,31]
    bool d2 = (qh < 32);             // right child [32,63]
    const float* Lrow = d1 ? &nemb[NCC][0] : &tw[1][0];
    const float* Rrow = d2 ? &nemb[NCC][0] : &tw[2][0];
    float o0, o1;
    combine8_core(Lrow, Rrow, w, k, qr, u, o0, o1);
    if (t < 8) ((float2*)&tw[0][0])[u] = make_float2(o0, o1);
}

extern "C" __global__ __attribute__((amdgpu_flat_work_group_size(256, 256)))
void seg_tree_kernel(
    const float* __restrict__ emb,
    const float* __restrict__ W_lin,
    const float* __restrict__ W_rule,
    const int*  __restrict__ x,
    const int*  __restrict__ qlo_g,
    const int*  __restrict__ qhi_g,
    float* __restrict__ out,
    int bsz)
{
    __shared__ __align__(16) float nemb[NCC + 1][DP];
    __shared__ __align__(16) float tree[EPB][NTREE][DP];

    const int tb = threadIdx.x;
    const int wv = tb >> 6;
    const int t  = tb & 63;
    int b = blockIdx.x * EPB + wv;
    const bool active = (b < bsz);
    if (!active) b = bsz - 1;                 // clamp: redundant work, store guarded

    const int k = t & 1, qr = (t >> 1) & 3, u = t & 7, g = t >> 3;
    float (*tw)[DP] = tree[wv];

    const int ql = qlo_g[b], qh = qhi_g[b];

    int xA[4], xB[4];
    #pragma unroll
    for (int st = 0; st < 4; ++st) {
        xA[st] = x[b * LL + st * 16 + 2 * g];
        xB[st] = x[b * LL + st * 16 + 2 * g + 1];
    }
    int piB = (((t >> 3) & 1) ? qh : ql) >> 1;
    int xq1 = x[b * LL + 2 * piB], xq2 = x[b * LL + 2 * piB + 1];

    // ---- per-lane weights: rows 4qr..4qr+3 of W_rule[k]; row 15 zeroed ----
    float w[4][DD];
    #pragma unroll
    for (int ri = 0; ri < 4; ++ri) {
        int i = 4 * qr + ri;
        bool valid = (i < DD);
        const float* src = W_rule + k * DD * DD + (valid ? i * DD : 0);
        #pragma unroll
        for (int j = 0; j < DD; ++j) w[ri][j] = valid ? src[j] : 0.0f;
    }
    #pragma unroll
    for (int ri = 0; ri < 4; ++ri)
        #pragma unroll
        for (int j = 0; j < DD; ++j)
            asm("" : "+v"(w[ri][j]));          // non-volatile pin: materialize once

    // ---- normalize emb rows into LDS once per block; pad col15 = 0 ----
    if (tb < NCC + 1) {
        float v[DD]; float ssum = 0.f;
        #pragma unroll
        for (int d = 0; d < DD; ++d) { v[d] = emb[tb * DD + d]; ssum += v[d] * v[d]; }
        float inv = __builtin_amdgcn_rsqf(ssum * (1.0f / DD) + 1e-6f);
        #pragma unroll
        for (int d = 0; d < DD; ++d) nemb[tb][d] = v[d] * inv;
        nemb[tb][DD] = 0.0f;
    }
    __syncthreads();                           // the only barrier

    // ==== DISCRIMINATOR: repeat the identical tree computation REPS times. ====
    // Iterations round-trip through LDS (tw), so hardware re-executes each one;
    // results are bit-identical every pass, final pass feeds the output.
    #pragma clang loop unroll(disable)
    for (int rep = 0; rep < REPS; ++rep) {
        build_level5(tw, nemb, w, xA, xB, k, qr, u, g);
        query_level5(tw, nemb, w, t, k, qr, u, ql, qh, xq1, xq2);

        build_level<4>(tw, w, k, qr, u, g);
        query_level<4>(tw, nemb, w, t, k, qr, u, ql, qh);

        build_level<3>(tw, w, k, qr, u, g);
        query_level<3>(tw, nemb, w, t, k, qr, u, ql, qh);

        build_level<2>(tw, w, k, qr, u, g);
        query_level<2>(tw, nemb, w, t, k, qr, u, ql, qh);

        build_level<1>(tw, w, k, qr, u, g);
        query_level<1>(tw, nemb, w, t, k, qr, u, ql, qh);

        query_level0(tw, nemb, w, t, k, qr, u, ql, qh);
    }

    // ---- output: out[b] = Q(root) @ W_lin.T ----
    if (active && t < NCC) {
        float acc = 0.f;
        #pragma unroll
        for (int d = 0; d < DD; ++d) acc = fmaf(tw[0][d], W_lin[t * DD + d], acc);
        out[b * NCC + t] = acc;
    }
}

extern "C" void kernel_launch(void* const* d_in, const int* in_sizes, int n_in,
                              void* d_out, int out_size, void* d_ws, size_t ws_size,
                              hipStream_t stream) {
    const float* emb    = (const float*)d_in[0];
    const float* W_lin  = (const float*)d_in[1];
    const float* W_rule = (const float*)d_in[2];
    const int*   x      = (const int*)d_in[3];
    const int*   qlo    = (const int*)d_in[4];
    const int*   qhi    = (const int*)d_in[5];
    float* outp = (float*)d_out;

    int bsz = in_sizes[3] / LL;               // 2048
    int nblk = (bsz + EPB - 1) / EPB;         // 512
    seg_tree_kernel<<<dim3(nblk), dim3(256), 0, stream>>>(
        emb, W_lin, W_rule, x, qlo, qhi, outp, bsz);
}

// Round 10
// 16.005 us; speedup vs baseline: 1.4871x; 1.4871x over previous
//
#include <hip/hip_runtime.h>
#include <math.h>

#define DD 15          // feature dim
#define DP 20          // padded LDS row stride (80B, float4-aligned)
#define LL 64          // leaves
#define NCC 10         // num classes
#define NTREE 63       // internal nodes only (levels 0..5)
#define EPB 4          // batch elements per block (1 per wave)

// ---- DPP cross-lane (VALU pipe, no LDS) ----
__device__ __forceinline__ float dpp_xor1(float x) {   // quad_perm [1,0,3,2]
    return __int_as_float(__builtin_amdgcn_update_dpp(0, __float_as_int(x), 0xB1, 0xF, 0xF, true));
}
__device__ __forceinline__ float dpp_xor2(float x) {   // quad_perm [2,3,0,1]
    return __int_as_float(__builtin_amdgcn_update_dpp(0, __float_as_int(x), 0x4E, 0xF, 0xF, true));
}
__device__ __forceinline__ float dpp_hmirror(float x) { // row_half_mirror: u -> u^7 within 8
    return __int_as_float(__builtin_amdgcn_update_dpp(0, __float_as_int(x), 0x141, 0xF, 0xF, true));
}

// combine at one parent: 8 lanes cooperate.
// k = t&1 (W matrix), qr = (t>>1)&3 (4 A-rows), u = t&7 (2 output dims)
__device__ __forceinline__ void combine8_core(const float* Lrow, const float* Rrow,
                                              const float w[4][DD], int k, int qr, int u,
                                              float& o0, float& o1)
{
    float4 R0 = ((const float4*)Rrow)[0];
    float4 R1 = ((const float4*)Rrow)[1];
    float4 R2 = ((const float4*)Rrow)[2];
    float4 R3 = ((const float4*)Rrow)[3];          // .w = pad col15 = 0
    float4 Aq = ((const float4*)Lrow)[qr];         // A dims 4qr..4qr+3 (row15 pad = 0)
    float Bv[DD] = {R0.x,R0.y,R0.z,R0.w, R1.x,R1.y,R1.z,R1.w,
                    R2.x,R2.y,R2.z,R2.w, R3.x,R3.y,R3.z};
    float Av[4] = {Aq.x, Aq.y, Aq.z, Aq.w};

    float p = 0.f;
    #pragma unroll
    for (int ri = 0; ri < 4; ++ri) {
        float dA = 0.f, dB = 0.f;                  // 2-way split: chain depth 8 not 15
        #pragma unroll
        for (int j = 0; j < 8; ++j)  dA = fmaf(w[ri][j], Bv[j], dA);
        #pragma unroll
        for (int j = 8; j < DD; ++j) dB = fmaf(w[ri][j], Bv[j], dB);
        p = fmaf(Av[ri], dA + dB, p);              // invalid row 15: w==0, Av==0
    }
    // reduce partials over qr bits (1,2) and swap k — all DPP
    float a    = p + dpp_xor2(p);
    float hma  = dpp_hmirror(a);
    float self = a + dpp_xor1(hma);
    float oth  = dpp_xor1(a) + hma;
    float mx = fmaxf(self, oth);
    float es = __expf(self - mx), eo = __expf(oth - mx);
    float rs = __builtin_amdgcn_rcpf(es + eo);
    float aS = es * rs, aO = eo * rs;
    float a0 = (k == 0) ? aS : aO;                 // alpha for W0 (left child)
    float a1 = (k == 0) ? aO : aS;

    float2 lm = ((const float2*)Lrow)[u];          // dims 2u, 2u+1
    float2 rm = ((const float2*)Rrow)[u];
    float v0 = a0 * lm.x + a1 * rm.x;
    float v1 = a0 * lm.y + a1 * rm.y;              // u==7: dim15 = 0
    float ss = v0 * v0 + v1 * v1;
    ss += dpp_xor1(ss);
    ss += dpp_xor2(ss);
    ss += dpp_hmirror(ss);
    float inv = __builtin_amdgcn_rsqf(ss * (1.0f / DD) + 1e-6f);
    o0 = v0 * inv; o1 = v1 * inv;
}

// ---- build level 5: children are nemb rows selected by preloaded x indices ----
__device__ __forceinline__ void build_level5(float (*tw)[DP], const float (*nemb)[DP],
                                             const float w[4][DD],
                                             const int xA[4], const int xB[4],
                                             int k, int qr, int u, int g)
{
    #pragma unroll
    for (int st = 0; st < 4; ++st) {
        int pi = st * 8 + g;
        float o0, o1;
        combine8_core(&nemb[xA[st]][0], &nemb[xB[st]][0], w, k, qr, u, o0, o1);
        ((float2*)&tw[31 + pi][0])[u] = make_float2(o0, o1);
    }
}

// ---- query level 5: boundary nodes; children are leaves (nemb rows or inf) ----
__device__ __forceinline__ void query_level5(float (*tw)[DP], const float (*nemb)[DP],
                                             const float w[4][DD], int t, int k, int qr, int u,
                                             int ql, int qh, int xq1, int xq2)
{
    const int g2 = (t >> 3) & 1;
    int bnd = g2 ? qh : ql;
    int piB = bnd >> 1;
    int lo = 2 * piB, hi = lo + 1;
    bool full = (ql <= lo) && (qh >= hi);
    bool d1 = (ql > lo) || (qh < lo);
    bool d2 = (ql > hi) || (qh < hi);
    const float* Lrow = d1 ? &nemb[NCC][0] : &nemb[xq1][0];
    const float* Rrow = d2 ? &nemb[NCC][0] : &nemb[xq2][0];
    float o0, o1;
    combine8_core(Lrow, Rrow, w, k, qr, u, o0, o1);
    bool we = (!full) && (t < 16) && (g2 == 0 || piB != (ql >> 1));
    if (we) ((float2*)&tw[31 + piB][0])[u] = make_float2(o0, o1);
}

// ---- generic build (levels 1..4) ----
template<int LVL>
__device__ __forceinline__ void build_level(float (*tw)[DP], const float w[4][DD],
                                            int k, int qr, int u, int g)
{
    constexpr int n = 1 << LVL, first = n - 1, nst = (n + 7) / 8;
    #pragma unroll
    for (int st = 0; st < nst; ++st) {
        int pi0 = st * 8 + g;
        int pi = (n < 8) ? ((pi0 < n) ? pi0 : 0) : pi0;   // clamp keeps reads in-bounds
        int p = first + pi;
        float o0, o1;
        combine8_core(&tw[2 * p + 1][0], &tw[2 * p + 2][0], w, k, qr, u, o0, o1);
        if (pi0 < n)
            ((float2*)&tw[p][0])[u] = make_float2(o0, o1);
    }
}

// ---- generic query (levels 1..4): children in tree ----
template<int LVL>
__device__ __forceinline__ void query_level(float (*tw)[DP], const float (*nemb)[DP],
                                            const float w[4][DD], int t, int k, int qr, int u,
                                            int ql, int qh)
{
    constexpr int first = (1 << LVL) - 1;
    constexpr int sh = 6 - LVL;
    constexpr int shc = sh - 1;
    const int g2 = (t >> 3) & 1;
    int bnd = g2 ? qh : ql;
    int pi = bnd >> sh;
    int lo = pi << sh, hi = lo + (1 << sh) - 1;
    bool full = (ql <= lo) && (qh >= hi);
    int p = first + pi;
    int ci1 = 2 * pi, ci2 = 2 * pi + 1;
    int lo1 = ci1 << shc, hi1 = lo1 + (1 << shc) - 1;
    int lo2 = ci2 << shc, hi2 = lo2 + (1 << shc) - 1;
    bool d1 = (ql > hi1) || (qh < lo1);
    bool d2 = (ql > hi2) || (qh < lo2);
    const float* Lrow = d1 ? &nemb[NCC][0] : &tw[2 * p + 1][0];
    const float* Rrow = d2 ? &nemb[NCC][0] : &tw[2 * p + 2][0];
    float o0, o1;
    combine8_core(Lrow, Rrow, w, k, qr, u, o0, o1);
    bool we = (!full) && (t < 16) && (g2 == 0 || pi != (ql >> sh));
    if (we) ((float2*)&tw[p][0])[u] = make_float2(o0, o1);
}

// ---- query level 0: always write (covers the root-full case) ----
__device__ __forceinline__ void query_level0(float (*tw)[DP], const float (*nemb)[DP],
                                             const float w[4][DD], int t, int k, int qr, int u,
                                             int ql, int qh)
{
    bool d1 = (ql > 31);             // left child [0,31]
    bool d2 = (qh < 32);             // right child [32,63]
    const float* Lrow = d1 ? &nemb[NCC][0] : &tw[1][0];
    const float* Rrow = d2 ? &nemb[NCC][0] : &tw[2][0];
    float o0, o1;
    combine8_core(Lrow, Rrow, w, k, qr, u, o0, o1);
    if (t < 8) ((float2*)&tw[0][0])[u] = make_float2(o0, o1);
}

extern "C" __global__ __attribute__((amdgpu_flat_work_group_size(256, 256)))
void seg_tree_kernel(
    const float* __restrict__ emb,
    const float* __restrict__ W_lin,
    const float* __restrict__ W_rule,
    const int*  __restrict__ x,
    const int*  __restrict__ qlo_g,
    const int*  __restrict__ qhi_g,
    float* __restrict__ out,
    int bsz)
{
    __shared__ __align__(16) float nemb[NCC + 1][DP];
    __shared__ __align__(16) float tree[EPB][NTREE][DP];

    const int tb = threadIdx.x;
    const int wv = tb >> 6;
    const int t  = tb & 63;
    int b = blockIdx.x * EPB + wv;
    const bool active = (b < bsz);
    if (!active) b = bsz - 1;                 // clamp: redundant work, store guarded

    const int k = t & 1, qr = (t >> 1) & 3, u = t & 7, g = t >> 3;
    float (*tw)[DP] = tree[wv];

    const int ql = qlo_g[b], qh = qhi_g[b];
    int xA[4], xB[4];
    #pragma unroll
    for (int st = 0; st < 4; ++st) {
        xA[st] = x[b * LL + st * 16 + 2 * g];
        xB[st] = x[b * LL + st * 16 + 2 * g + 1];
    }
    int piB = (((t >> 3) & 1) ? qh : ql) >> 1;
    int xq1 = x[b * LL + 2 * piB], xq2 = x[b * LL + 2 * piB + 1];

    // ---- per-lane weights: rows 4qr..4qr+3 of W_rule[k]; row 15 zeroed ----
    float w[4][DD];
    #pragma unroll
    for (int ri = 0; ri < 4; ++ri) {
        int i = 4 * qr + ri;
        bool valid = (i < DD);
        const float* src = W_rule + k * DD * DD + (valid ? i * DD : 0);
        #pragma unroll
        for (int j = 0; j < DD; ++j) w[ri][j] = valid ? src[j] : 0.0f;
    }
    #pragma unroll
    for (int ri = 0; ri < 4; ++ri)
        #pragma unroll
        for (int j = 0; j < DD; ++j)
            asm("" : "+v"(w[ri][j]));          // non-volatile pin: materialize once

    // ---- normalize emb rows into LDS once per block; pad col15 = 0 ----
    if (tb < NCC + 1) {
        float v[DD]; float ssum = 0.f;
        #pragma unroll
        for (int d = 0; d < DD; ++d) { v[d] = emb[tb * DD + d]; ssum += v[d] * v[d]; }
        float inv = __builtin_amdgcn_rsqf(ssum * (1.0f / DD) + 1e-6f);
        #pragma unroll
        for (int d = 0; d < DD; ++d) nemb[tb][d] = v[d] * inv;
        nemb[tb][DD] = 0.0f;
    }
    __syncthreads();                           // the only barrier

    // ---- 6 fused phases; waves fully independent, no barriers ----
    build_level5(tw, nemb, w, xA, xB, k, qr, u, g);
    query_level5(tw, nemb, w, t, k, qr, u, ql, qh, xq1, xq2);

    build_level<4>(tw, w, k, qr, u, g);
    query_level<4>(tw, nemb, w, t, k, qr, u, ql, qh);

    build_level<3>(tw, w, k, qr, u, g);
    query_level<3>(tw, nemb, w, t, k, qr, u, ql, qh);

    build_level<2>(tw, w, k, qr, u, g);
    query_level<2>(tw, nemb, w, t, k, qr, u, ql, qh);

    build_level<1>(tw, w, k, qr, u, g);
    query_level<1>(tw, nemb, w, t, k, qr, u, ql, qh);

    query_level0(tw, nemb, w, t, k, qr, u, ql, qh);

    // ---- output: out[b] = Q(root) @ W_lin.T ----
    if (active && t < NCC) {
        float acc = 0.f;
        #pragma unroll
        for (int d = 0; d < DD; ++d) acc = fmaf(tw[0][d], W_lin[t * DD + d], acc);
        out[b * NCC + t] = acc;
    }
}

extern "C" void kernel_launch(void* const* d_in, const int* in_sizes, int n_in,
                              void* d_out, int out_size, void* d_ws, size_t ws_size,
                              hipStream_t stream) {
    const float* emb    = (const float*)d_in[0];
    const float* W_lin  = (const float*)d_in[1];
    const float* W_rule = (const float*)d_in[2];
    const int*   x      = (const int*)d_in[3];
    const int*   qlo    = (const int*)d_in[4];
    const int*   qhi    = (const int*)d_in[5];
    float* outp = (float*)d_out;

    int bsz = in_sizes[3] / LL;               // 2048
    int nblk = (bsz + EPB - 1) / EPB;         // 512
    seg_tree_kernel<<<dim3(nblk), dim3(256), 0, stream>>>(
        emb, W_lin, W_rule, x, qlo, qhi, outp, bsz);
}